// Round 8
// baseline (1497.780 us; speedup 1.0000x reference)
//
#include <hip/hip_runtime.h>
#include <hip/hip_bf16.h>

#define B_   4
#define IC   64
#define OC   128
#define HH   128
#define WW   128
#define HP   130      // padded H/W for sampling
#define XOF  384      // x_off spatial (128*3)
#define XPAD 388      // padded x-dim of granule layout
#define OH2  382      // final output spatial

typedef __attribute__((ext_vector_type(4))) float f32x4;
typedef __attribute__((ext_vector_type(8))) __bf16 bf16x8;
typedef __attribute__((ext_vector_type(8))) unsigned short us8;
typedef __attribute__((ext_vector_type(4), aligned(4))) float f32x4u;

__device__ __forceinline__ void gload16(const void* gsrc, void* ldst) {
    __builtin_amdgcn_global_load_lds(
        (const __attribute__((address_space(1))) void*)gsrc,
        (__attribute__((address_space(3))) void*)ldst, 16, 0, 0);
}

// ---------------------------------------------------------------------------
// DIAGNOSTIC ROUND: kernel bodies byte-identical to R7. Extra grid dims
// (blockIdx.y = rep) duplicate the full work; every rep writes bit-identical
// values, so output is unchanged while single-dispatch durations rise above
// the ~190us poison-fill floor and appear in rocprof top-5 WITH counters.
// ---------------------------------------------------------------------------

// Kernel A (R1/R7): offset conv, thread-per-pixel, all 64 ic. rep = blockIdx.y.
__global__ __launch_bounds__(256) void offset_conv(const float* __restrict__ x,
                                                   const float* __restrict__ w_p,
                                                   const float* __restrict__ b_p,
                                                   float* __restrict__ off) {
    int t  = blockIdx.x * 256 + threadIdx.x;       // 4*128*128 = 65536 exact
    int px = t % WW;
    int py = (t / WW) % HH;
    int b  = t / (WW * HH);

    float acc[18];
#pragma unroll
    for (int co = 0; co < 18; ++co) acc[co] = b_p[co];

    const float* xb = x + (size_t)b * IC * HH * WW;
    for (int ci = 0; ci < IC; ++ci) {
        const float* xc = xb + (size_t)ci * HH * WW;
        float xv[9];
#pragma unroll
        for (int ky = 0; ky < 3; ++ky) {
            int yy = py + ky - 1;
            bool yok = (yy >= 0) && (yy < HH);
#pragma unroll
            for (int kx = 0; kx < 3; ++kx) {
                int xx = px + kx - 1;
                bool ok = yok && (xx >= 0) && (xx < WW);
                xv[ky * 3 + kx] = ok ? xc[yy * WW + xx] : 0.f;
            }
        }
#pragma unroll
        for (int co = 0; co < 18; ++co) {
            const float* wrow = w_p + ((size_t)co * IC + ci) * 9;
#pragma unroll
            for (int k = 0; k < 9; ++k)
                acc[co] = fmaf(wrow[k], xv[k], acc[co]);
        }
    }

    float* ob = off + (size_t)b * 18 * HH * WW + (size_t)py * WW + px;
#pragma unroll
    for (int co = 0; co < 18; ++co) ob[(size_t)co * HH * WW] = acc[co];
}

// Kernel P (byte-identical): weights -> bf16 K-step tiles.
__global__ __launch_bounds__(256) void prep_w(const float* __restrict__ wc,
                                              unsigned short* __restrict__ Bt) {
    int t = blockIdx.x * 256 + threadIdx.x;
    if (t >= 18 * 4 * 128 * 8) return;
    int e  = t & 7;
    int oc = (t >> 3) & 127;
    int kg = (t >> 10) & 3;
    int s  = t >> 12;
    int ic = ((s & 1) << 5) + (kg << 3) + e;
    int kpos = s >> 1;
    int ky = kpos / 3, kx = kpos % 3;
    float v = wc[(((size_t)oc * IC + ic) * 3 + ky) * 3 + kx];
    __hip_bfloat16 h = __float2bfloat16(v);
    Bt[t] = reinterpret_cast<unsigned short&>(h);
}

// Kernel B (byte-identical): bilinear sampling -> granule layout. rep = blockIdx.y.
__global__ __launch_bounds__(256) void sample_g(const float* __restrict__ x,
                                                const float* __restrict__ off,
                                                unsigned short* __restrict__ xoff,
                                                int b0, int nwg) {
    int orig = blockIdx.x;
    int chunk = nwg >> 3;
    int wg = (orig & 7) * chunk + (orig >> 3);

    int xt  = wg % 12;
    int tmp = wg / 12;
    int yy  = tmp % XOF;
    int bl  = tmp / XOF;
    int b   = b0 + bl;
    int xx0 = xt * 32;

    int t  = threadIdx.x;
    int xl = t & 31;
    int cg = t >> 5;
    int xx = xx0 + xl;

    int j = xx / 3, kw = xx % 3;
    int i = yy / 3, kh = yy % 3;
    int n = kh * 3 + kw;

    const float* offb = off + (size_t)b * 18 * HH * WW + (size_t)i * WW + j;
    float offr = offb[(size_t)n * HH * WW];
    float offc = offb[(size_t)(n + 9) * HH * WW];

    float pr = (float)(i + kh) + offr;
    float pc = (float)(j + kw) + offc;

    float r0f = floorf(pr), c0f = floorf(pc);
    int r0 = min(max((int)r0f, 0), HP - 1);
    int c0 = min(max((int)c0f, 0), HP - 1);
    int r1 = min(max((int)(r0f + 1.f), 0), HP - 1);
    int c1 = min(max((int)(c0f + 1.f), 0), HP - 1);

    float prc = fminf(fmaxf(pr, 0.f), (float)(HP - 1));
    float pcc = fminf(fmaxf(pc, 0.f), (float)(HP - 1));

    float glt = (1.f + ((float)r0 - prc)) * (1.f + ((float)c0 - pcc));
    float grb = (1.f - ((float)r1 - prc)) * (1.f - ((float)c1 - pcc));
    float glb = (1.f + ((float)r0 - prc)) * (1.f - ((float)c1 - pcc));
    float grt = (1.f - ((float)r1 - prc)) * (1.f + ((float)c0 - pcc));

    int rr0 = r0 - 1, cc0 = c0 - 1, rr1 = r1 - 1, cc1 = c1 - 1;
    bool r0ok = (rr0 >= 0) && (rr0 < HH);
    bool r1ok = (rr1 >= 0) && (rr1 < HH);
    bool c0ok = (cc0 >= 0) && (cc0 < WW);
    bool c1ok = (cc1 >= 0) && (cc1 < WW);

    float wlt = (r0ok && c0ok) ? glt : 0.f;
    float wrb = (r1ok && c1ok) ? grb : 0.f;
    float wlb = (r0ok && c1ok) ? glb : 0.f;
    float wrt = (r1ok && c0ok) ? grt : 0.f;
    int olt = (r0ok && c0ok) ? (rr0 * WW + cc0) : 0;
    int orb = (r1ok && c1ok) ? (rr1 * WW + cc1) : 0;
    int olb = (r0ok && c1ok) ? (rr0 * WW + cc1) : 0;
    int ort = (r1ok && c0ok) ? (rr1 * WW + cc0) : 0;

    const float* xg = x + ((size_t)b * IC + cg * 8) * HH * WW;

    us8 res;
#pragma unroll
    for (int e = 0; e < 8; ++e) {
        const float* xc = xg + (size_t)e * HH * WW;
        float v = wlt * xc[olt] + wrb * xc[orb] + wlb * xc[olb] + wrt * xc[ort];
        __hip_bfloat16 h = __float2bfloat16(v);
        res[e] = reinterpret_cast<unsigned short&>(h);
    }

    size_t di = ((((size_t)bl * XOF + yy) * 8 + cg) * XPAD + xx) * 8;
    *(us8*)(xoff + di) = res;
}

// Kernel C (byte-identical): bf16 MFMA implicit-GEMM conv. rep = blockIdx.y.
__global__ __launch_bounds__(256) void conv2_mfma(const unsigned short* __restrict__ xoff,
                                                  const unsigned short* __restrict__ Bt,
                                                  float* __restrict__ out,
                                                  int b0, int nwg) {
    __shared__ __align__(16) char lds[40960];
    // A slab buf: [cg:4][px:192][16B] = 12288 B at buf*12288
    // B buf:      [kg:4][oc:128][16B] =  8192 B at 24576 + buf*8192

    // bijective XCD-chunk swizzle (m204)
    int orig = blockIdx.x;
    int q = nwg >> 3, r = nwg & 7;
    int xcd = orig & 7, loc = orig >> 3;
    int wgid = (xcd < r ? xcd * (q + 1) : r * (q + 1) + (xcd - r) * q) + loc;

    int xt  = wgid % 3;
    int tmp = wgid / 3;
    int oy  = tmp % OH2;
    int bl  = tmp / OH2;
    int x0  = xt << 7;

    int tid  = threadIdx.x;
    int wave = tid >> 6, lane = tid & 63;
    int wm = wave >> 1;            // px half
    int wn = wave & 1;             // oc half
    int lr = lane & 15, lc = lane >> 4;

    const char* xb = (const char*)xoff + (size_t)bl * ((size_t)XOF * 8 * XPAD * 16);
    const char* bt = (const char*)Bt;

    f32x4 acc[4][4];
#pragma unroll
    for (int mf = 0; mf < 4; ++mf)
#pragma unroll
        for (int nf = 0; nf < 4; ++nf)
            acc[mf][nf] = (f32x4){0.f, 0.f, 0.f, 0.f};

    auto stageA = [&](int abuf, int s6, int third) {
        int ky  = s6 >> 1;
        int ich = s6 & 1;
        int L   = third * 4 + wave;
        int cg  = L / 3, seg = L % 3;
        const char* src = xb +
            (((size_t)(oy + ky) * 8 + ich * 4 + cg) * XPAD + x0 + seg * 64 + lane) * 16;
        char* dst = lds + abuf * 12288 + (cg * 192 + seg * 64) * 16;
        gload16(src, dst);
    };
    auto stageA_full = [&](int abuf, int s6) {
#pragma unroll
        for (int qq = 0; qq < 3; ++qq) {
            int ky  = s6 >> 1;
            int ich = s6 & 1;
            int L   = wave * 3 + qq;
            int cg  = L / 3, seg = L % 3;
            const char* src = xb +
                (((size_t)(oy + ky) * 8 + ich * 4 + cg) * XPAD + x0 + seg * 64 + lane) * 16;
            char* dst = lds + abuf * 12288 + (cg * 192 + seg * 64) * 16;
            gload16(src, dst);
        }
    };
    auto stageB = [&](int bbuf, int t) {
        int s6 = t / 3, kx = t % 3;
        int sB = ((s6 >> 1) * 3 + kx) * 2 + (s6 & 1);
        const char* bsrc = bt + (size_t)sB * 8192;
#pragma unroll
        for (int g2 = 0; g2 < 2; ++g2) {
            int g = wave * 2 + g2;
            gload16(bsrc + (size_t)g * 1024 + lane * 16,
                    lds + 24576 + bbuf * 8192 + g * 1024);
        }
    };

    auto compute = [&](int abuf, int bbuf, int kx) {
        const char* abase = lds + abuf * 12288;
        const char* bbase = lds + 24576 + bbuf * 8192;
        bf16x8 af[4], bfr[4];
#pragma unroll
        for (int mf = 0; mf < 4; ++mf)
            af[mf] = *(const bf16x8*)(abase +
                (lc * 192 + wm * 64 + mf * 16 + lr + kx) * 16);
#pragma unroll
        for (int nf = 0; nf < 4; ++nf)
            bfr[nf] = *(const bf16x8*)(bbase +
                (lc * 128 + wn * 64 + nf * 16 + lr) * 16);
#pragma unroll
        for (int mf = 0; mf < 4; ++mf)
#pragma unroll
            for (int nf = 0; nf < 4; ++nf)
                acc[mf][nf] = __builtin_amdgcn_mfma_f32_16x16x32_bf16(
                    af[mf], bfr[nf], acc[mf][nf], 0, 0, 0);
    };

    stageA_full(0, 0);
    stageB(0, 0);
    __syncthreads();

    int abuf = 0, bbuf = 0;
    for (int t = 0; t < 18; ++t) {
        int s6 = t / 3, kx = t % 3;
        if (t + 1 < 18) stageB(bbuf ^ 1, t + 1);
        if (s6 + 1 < 6) stageA(abuf ^ 1, s6 + 1, kx);
        compute(abuf, bbuf, kx);
        __syncthreads();
        bbuf ^= 1;
        if (kx == 2) abuf ^= 1;
    }

    int b = b0 + bl;
#pragma unroll
    for (int mf = 0; mf < 4; ++mf) {
        int ox0 = x0 + wm * 64 + mf * 16 + (lc << 2);
#pragma unroll
        for (int nf = 0; nf < 4; ++nf) {
            int oc = wn * 64 + nf * 16 + lr;
            float* po = out + (((size_t)b * OC + oc) * OH2 + oy) * OH2 + ox0;
            if (ox0 + 3 < OH2) {
                *(f32x4u*)po = acc[mf][nf];
            } else {
#pragma unroll
                for (int rr = 0; rr < 4; ++rr)
                    if (ox0 + rr < OH2) po[rr] = acc[mf][nf][rr];
            }
        }
    }
}

// ---------------------------------------------------------------------------
extern "C" void kernel_launch(void* const* d_in, const int* in_sizes, int n_in,
                              void* d_out, int out_size, void* d_ws, size_t ws_size,
                              hipStream_t stream) {
    const float* x      = (const float*)d_in[0];
    const float* w_p    = (const float*)d_in[1];
    const float* b_p    = (const float*)d_in[2];
    const float* w_conv = (const float*)d_in[3];
    float* out = (float*)d_out;

    const size_t offElems = (size_t)B_ * 18 * HH * WW;          // f32
    const size_t btElems  = (size_t)18 * 4 * 128 * 8;           // bf16
    const size_t xofElems = (size_t)XOF * 8 * XPAD * 8;         // bf16 per batch
    const size_t slack    = 16384;

    float* off = (float*)d_ws;
    unsigned short* Bt   = (unsigned short*)(off + offElems);
    unsigned short* xoff = Bt + btElems;

    const size_t headBytes = offElems * 4 + btElems * 2;
    const bool allBatch = ws_size >= headBytes + 4 * xofElems * 2 + slack;

    prep_w<<<(int)((btElems + 255) / 256), 256, 0, stream>>>(w_conv, Bt);

    // DIAGNOSTIC: rep-duplicated dispatches (bit-identical redundant work).
    dim3 og((B_ * HH * WW) / 256, 16);             // offset x16
    offset_conv<<<og, 256, 0, stream>>>(x, w_p, b_p, off);

    if (allBatch) {
        int snwg = 12 * XOF * B_;                  // 18432
        dim3 sg(snwg, 8);                          // sample x8
        sample_g<<<sg, 256, 0, stream>>>(x, off, xoff, 0, snwg);
        int cnwg = 3 * OH2 * B_;                   // 4584
        dim3 cg(cnwg, 2);                          // conv2 x2
        conv2_mfma<<<cg, 256, 0, stream>>>(xoff, Bt, out, 0, cnwg);
    } else {
        for (int b = 0; b < B_; ++b) {
            int snwg = 12 * XOF;                   // 4608
            sample_g<<<dim3(snwg, 1), 256, 0, stream>>>(x, off, xoff, b, snwg);
            int cnwg = 3 * OH2;                    // 1146
            conv2_mfma<<<dim3(cnwg, 1), 256, 0, stream>>>(xoff, Bt, out, b, cnwg);
        }
    }
}

// Round 9
// 793.775 us; speedup vs baseline: 1.8869x; 1.8869x over previous
//
#include <hip/hip_runtime.h>
#include <hip/hip_bf16.h>

#define B_   4
#define IC   64
#define OC   128
#define HH   128
#define WW   128
#define HP   130      // padded H/W for sampling
#define XOF  384      // x_off spatial (128*3)
#define XPAD 388      // padded x-dim of granule layout
#define OH2  382      // final output spatial

typedef __attribute__((ext_vector_type(4))) float f32x4;
typedef __attribute__((ext_vector_type(8))) __bf16 bf16x8;
typedef __attribute__((ext_vector_type(8))) unsigned short us8;
typedef __attribute__((ext_vector_type(4), aligned(4))) float f32x4u;
typedef __attribute__((ext_vector_type(2), aligned(4))) float f32x2u;

__device__ __forceinline__ void gload16(const void* gsrc, void* ldst) {
    __builtin_amdgcn_global_load_lds(
        (const __attribute__((address_space(1))) void*)gsrc,
        (__attribute__((address_space(3))) void*)ldst, 16, 0, 0);
}

// ---------------------------------------------------------------------------
// Kernel A (R1/R7, unchanged): offset conv, thread-per-pixel, all 64 ic.
// ---------------------------------------------------------------------------
__global__ __launch_bounds__(256) void offset_conv(const float* __restrict__ x,
                                                   const float* __restrict__ w_p,
                                                   const float* __restrict__ b_p,
                                                   float* __restrict__ off) {
    int t  = blockIdx.x * 256 + threadIdx.x;       // 4*128*128 = 65536 exact
    int px = t % WW;
    int py = (t / WW) % HH;
    int b  = t / (WW * HH);

    float acc[18];
#pragma unroll
    for (int co = 0; co < 18; ++co) acc[co] = b_p[co];

    const float* xb = x + (size_t)b * IC * HH * WW;
    for (int ci = 0; ci < IC; ++ci) {
        const float* xc = xb + (size_t)ci * HH * WW;
        float xv[9];
#pragma unroll
        for (int ky = 0; ky < 3; ++ky) {
            int yy = py + ky - 1;
            bool yok = (yy >= 0) && (yy < HH);
#pragma unroll
            for (int kx = 0; kx < 3; ++kx) {
                int xx = px + kx - 1;
                bool ok = yok && (xx >= 0) && (xx < WW);
                xv[ky * 3 + kx] = ok ? xc[yy * WW + xx] : 0.f;
            }
        }
#pragma unroll
        for (int co = 0; co < 18; ++co) {
            const float* wrow = w_p + ((size_t)co * IC + ci) * 9;
#pragma unroll
            for (int k = 0; k < 9; ++k)
                acc[co] = fmaf(wrow[k], xv[k], acc[co]);
        }
    }

    float* ob = off + (size_t)b * 18 * HH * WW + (size_t)py * WW + px;
#pragma unroll
    for (int co = 0; co < 18; ++co) ob[(size_t)co * HH * WW] = acc[co];
}

// ---------------------------------------------------------------------------
// Kernel P (unchanged): weights -> bf16 K-step tiles.
// ---------------------------------------------------------------------------
__global__ __launch_bounds__(256) void prep_w(const float* __restrict__ wc,
                                              unsigned short* __restrict__ Bt) {
    int t = blockIdx.x * 256 + threadIdx.x;
    if (t >= 18 * 4 * 128 * 8) return;
    int e  = t & 7;
    int oc = (t >> 3) & 127;
    int kg = (t >> 10) & 3;
    int s  = t >> 12;
    int ic = ((s & 1) << 5) + (kg << 3) + e;
    int kpos = s >> 1;
    int ky = kpos / 3, kx = kpos % 3;
    float v = wc[(((size_t)oc * IC + ic) * 3 + ky) * 3 + kx];
    __hip_bfloat16 h = __float2bfloat16(v);
    Bt[t] = reinterpret_cast<unsigned short&>(h);
}

// ---------------------------------------------------------------------------
// Kernel B v2: bilinear sampling with PAIRED dwordx2 corner gathers.
// Weights are separable: R0,R1 (rows) x C0,C1 (cols) with validity folded
// into the factors. Fast path (cc1==cc0+1, both in [0,127]): the two corners
// of each row are one float2 load -> 16 loads/thread instead of 32.
// Slow path (clamp-irregular columns, ~<5% of pixels): masked scalar loads,
// mathematically identical to R1-R7's version.
// ---------------------------------------------------------------------------
__global__ __launch_bounds__(256) void sample_g(const float* __restrict__ x,
                                                const float* __restrict__ off,
                                                unsigned short* __restrict__ xoff,
                                                int b0, int nwg) {
    int orig = blockIdx.x;
    int chunk = nwg >> 3;
    int wg = (orig & 7) * chunk + (orig >> 3);

    int xt  = wg % 12;
    int tmp = wg / 12;
    int yy  = tmp % XOF;
    int bl  = tmp / XOF;
    int b   = b0 + bl;
    int xx0 = xt * 32;

    int t  = threadIdx.x;
    int xl = t & 31;
    int cg = t >> 5;
    int xx = xx0 + xl;

    int j = xx / 3, kw = xx % 3;
    int i = yy / 3, kh = yy % 3;
    int n = kh * 3 + kw;

    const float* offb = off + (size_t)b * 18 * HH * WW + (size_t)i * WW + j;
    float offr = offb[(size_t)n * HH * WW];
    float offc = offb[(size_t)(n + 9) * HH * WW];

    float pr = (float)(i + kh) + offr;
    float pc = (float)(j + kw) + offc;

    float r0f = floorf(pr), c0f = floorf(pc);
    int r0 = min(max((int)r0f, 0), HP - 1);
    int c0 = min(max((int)c0f, 0), HP - 1);
    int r1 = min(max((int)(r0f + 1.f), 0), HP - 1);
    int c1 = min(max((int)(c0f + 1.f), 0), HP - 1);

    float prc = fminf(fmaxf(pr, 0.f), (float)(HP - 1));
    float pcc = fminf(fmaxf(pc, 0.f), (float)(HP - 1));

    // separable weights
    float R0 = 1.f + ((float)r0 - prc);
    float R1 = 1.f - ((float)r1 - prc);
    float C0 = 1.f + ((float)c0 - pcc);
    float C1 = 1.f - ((float)c1 - pcc);

    int rr0 = r0 - 1, cc0 = c0 - 1, rr1 = r1 - 1, cc1 = c1 - 1;
    if (!(rr0 >= 0 && rr0 < HH)) R0 = 0.f;
    if (!(rr1 >= 0 && rr1 < HH)) R1 = 0.f;
    int ra0 = min(max(rr0, 0), HH - 1);
    int ra1 = min(max(rr1, 0), HH - 1);

    const float* xg = x + ((size_t)b * IC + cg * 8) * HH * WW;
    us8 res;

    bool fastc = (cc0 >= 0) && (cc1 == cc0 + 1) && (cc1 <= WW - 1);
    if (fastc) {
        int o0 = ra0 * WW + cc0;
        int o1 = ra1 * WW + cc0;
#pragma unroll
        for (int e = 0; e < 8; ++e) {
            const float* xc = xg + (size_t)e * HH * WW;
            f32x2u f0 = *(const f32x2u*)(xc + o0);
            f32x2u f1 = *(const f32x2u*)(xc + o1);
            float v = R0 * (C0 * f0.x + C1 * f0.y) + R1 * (C0 * f1.x + C1 * f1.y);
            __hip_bfloat16 h = __float2bfloat16(v);
            res[e] = reinterpret_cast<unsigned short&>(h);
        }
    } else {
        float C0m = (cc0 >= 0 && cc0 < WW) ? C0 : 0.f;
        float C1m = (cc1 >= 0 && cc1 < WW) ? C1 : 0.f;
        int ca0 = min(max(cc0, 0), WW - 1);
        int ca1 = min(max(cc1, 0), WW - 1);
        int o00 = ra0 * WW + ca0, o01 = ra0 * WW + ca1;
        int o10 = ra1 * WW + ca0, o11 = ra1 * WW + ca1;
#pragma unroll
        for (int e = 0; e < 8; ++e) {
            const float* xc = xg + (size_t)e * HH * WW;
            float v = R0 * (C0m * xc[o00] + C1m * xc[o01]) +
                      R1 * (C0m * xc[o10] + C1m * xc[o11]);
            __hip_bfloat16 h = __float2bfloat16(v);
            res[e] = reinterpret_cast<unsigned short&>(h);
        }
    }

    size_t di = ((((size_t)bl * XOF + yy) * 8 + cg) * XPAD + xx) * 8;
    *(us8*)(xoff + di) = res;
}

// ---------------------------------------------------------------------------
// Kernel C (body byte-identical to R4-R8): bf16 MFMA implicit-GEMM conv.
// DIAGNOSTIC this round: launched with grid.y = 4 (rep-duplicated identical
// work, bit-identical writes) so its single-dispatch duration tops the
// rocprof table and returns full counters.
// ---------------------------------------------------------------------------
__global__ __launch_bounds__(256) void conv2_mfma(const unsigned short* __restrict__ xoff,
                                                  const unsigned short* __restrict__ Bt,
                                                  float* __restrict__ out,
                                                  int b0, int nwg) {
    __shared__ __align__(16) char lds[40960];
    // A slab buf: [cg:4][px:192][16B] = 12288 B at buf*12288
    // B buf:      [kg:4][oc:128][16B] =  8192 B at 24576 + buf*8192

    // bijective XCD-chunk swizzle (m204)
    int orig = blockIdx.x;
    int q = nwg >> 3, r = nwg & 7;
    int xcd = orig & 7, loc = orig >> 3;
    int wgid = (xcd < r ? xcd * (q + 1) : r * (q + 1) + (xcd - r) * q) + loc;

    int xt  = wgid % 3;
    int tmp = wgid / 3;
    int oy  = tmp % OH2;
    int bl  = tmp / OH2;
    int x0  = xt << 7;

    int tid  = threadIdx.x;
    int wave = tid >> 6, lane = tid & 63;
    int wm = wave >> 1;            // px half
    int wn = wave & 1;             // oc half
    int lr = lane & 15, lc = lane >> 4;

    const char* xb = (const char*)xoff + (size_t)bl * ((size_t)XOF * 8 * XPAD * 16);
    const char* bt = (const char*)Bt;

    f32x4 acc[4][4];
#pragma unroll
    for (int mf = 0; mf < 4; ++mf)
#pragma unroll
        for (int nf = 0; nf < 4; ++nf)
            acc[mf][nf] = (f32x4){0.f, 0.f, 0.f, 0.f};

    auto stageA = [&](int abuf, int s6, int third) {
        int ky  = s6 >> 1;
        int ich = s6 & 1;
        int L   = third * 4 + wave;
        int cg  = L / 3, seg = L % 3;
        const char* src = xb +
            (((size_t)(oy + ky) * 8 + ich * 4 + cg) * XPAD + x0 + seg * 64 + lane) * 16;
        char* dst = lds + abuf * 12288 + (cg * 192 + seg * 64) * 16;
        gload16(src, dst);
    };
    auto stageA_full = [&](int abuf, int s6) {
#pragma unroll
        for (int qq = 0; qq < 3; ++qq) {
            int ky  = s6 >> 1;
            int ich = s6 & 1;
            int L   = wave * 3 + qq;
            int cg  = L / 3, seg = L % 3;
            const char* src = xb +
                (((size_t)(oy + ky) * 8 + ich * 4 + cg) * XPAD + x0 + seg * 64 + lane) * 16;
            char* dst = lds + abuf * 12288 + (cg * 192 + seg * 64) * 16;
            gload16(src, dst);
        }
    };
    auto stageB = [&](int bbuf, int t) {
        int s6 = t / 3, kx = t % 3;
        int sB = ((s6 >> 1) * 3 + kx) * 2 + (s6 & 1);
        const char* bsrc = bt + (size_t)sB * 8192;
#pragma unroll
        for (int g2 = 0; g2 < 2; ++g2) {
            int g = wave * 2 + g2;
            gload16(bsrc + (size_t)g * 1024 + lane * 16,
                    lds + 24576 + bbuf * 8192 + g * 1024);
        }
    };

    auto compute = [&](int abuf, int bbuf, int kx) {
        const char* abase = lds + abuf * 12288;
        const char* bbase = lds + 24576 + bbuf * 8192;
        bf16x8 af[4], bfr[4];
#pragma unroll
        for (int mf = 0; mf < 4; ++mf)
            af[mf] = *(const bf16x8*)(abase +
                (lc * 192 + wm * 64 + mf * 16 + lr + kx) * 16);
#pragma unroll
        for (int nf = 0; nf < 4; ++nf)
            bfr[nf] = *(const bf16x8*)(bbase +
                (lc * 128 + wn * 64 + nf * 16 + lr) * 16);
#pragma unroll
        for (int mf = 0; mf < 4; ++mf)
#pragma unroll
            for (int nf = 0; nf < 4; ++nf)
                acc[mf][nf] = __builtin_amdgcn_mfma_f32_16x16x32_bf16(
                    af[mf], bfr[nf], acc[mf][nf], 0, 0, 0);
    };

    stageA_full(0, 0);
    stageB(0, 0);
    __syncthreads();

    int abuf = 0, bbuf = 0;
    for (int t = 0; t < 18; ++t) {
        int s6 = t / 3, kx = t % 3;
        if (t + 1 < 18) stageB(bbuf ^ 1, t + 1);
        if (s6 + 1 < 6) stageA(abuf ^ 1, s6 + 1, kx);
        compute(abuf, bbuf, kx);
        __syncthreads();
        bbuf ^= 1;
        if (kx == 2) abuf ^= 1;
    }

    int b = b0 + bl;
#pragma unroll
    for (int mf = 0; mf < 4; ++mf) {
        int ox0 = x0 + wm * 64 + mf * 16 + (lc << 2);
#pragma unroll
        for (int nf = 0; nf < 4; ++nf) {
            int oc = wn * 64 + nf * 16 + lr;
            float* po = out + (((size_t)b * OC + oc) * OH2 + oy) * OH2 + ox0;
            if (ox0 + 3 < OH2) {
                *(f32x4u*)po = acc[mf][nf];
            } else {
#pragma unroll
                for (int rr = 0; rr < 4; ++rr)
                    if (ox0 + rr < OH2) po[rr] = acc[mf][nf][rr];
            }
        }
    }
}

// ---------------------------------------------------------------------------
extern "C" void kernel_launch(void* const* d_in, const int* in_sizes, int n_in,
                              void* d_out, int out_size, void* d_ws, size_t ws_size,
                              hipStream_t stream) {
    const float* x      = (const float*)d_in[0];
    const float* w_p    = (const float*)d_in[1];
    const float* b_p    = (const float*)d_in[2];
    const float* w_conv = (const float*)d_in[3];
    float* out = (float*)d_out;

    const size_t offElems = (size_t)B_ * 18 * HH * WW;          // f32
    const size_t btElems  = (size_t)18 * 4 * 128 * 8;           // bf16
    const size_t xofElems = (size_t)XOF * 8 * XPAD * 8;         // bf16 per batch
    const size_t slack    = 16384;

    float* off = (float*)d_ws;
    unsigned short* Bt   = (unsigned short*)(off + offElems);
    unsigned short* xoff = Bt + btElems;

    const size_t headBytes = offElems * 4 + btElems * 2;
    const bool allBatch = ws_size >= headBytes + 4 * xofElems * 2 + slack;

    prep_w<<<(int)((btElems + 255) / 256), 256, 0, stream>>>(w_conv, Bt);
    offset_conv<<<(B_ * HH * WW) / 256, 256, 0, stream>>>(x, w_p, b_p, off);

    if (allBatch) {
        int snwg = 12 * XOF * B_;                 // 18432
        sample_g<<<snwg, 256, 0, stream>>>(x, off, xoff, 0, snwg);
        int cnwg = 3 * OH2 * B_;                  // 4584
        dim3 cg(cnwg, 4);                         // DIAGNOSTIC: conv2 x4
        conv2_mfma<<<cg, 256, 0, stream>>>(xoff, Bt, out, 0, cnwg);
    } else {
        for (int b = 0; b < B_; ++b) {
            int snwg = 12 * XOF;                  // 4608
            sample_g<<<snwg, 256, 0, stream>>>(x, off, xoff, b, snwg);
            int cnwg = 3 * OH2;                   // 1146
            conv2_mfma<<<dim3(cnwg, 1), 256, 0, stream>>>(xoff, Bt, out, b, cnwg);
        }
    }
}

// Round 10
// 313.262 us; speedup vs baseline: 4.7812x; 2.5339x over previous
//
#include <hip/hip_runtime.h>
#include <hip/hip_bf16.h>

#define B_   4
#define IC   64
#define OC   128
#define HH   128
#define WW   128
#define HP   130      // padded H/W for sampling
#define XOF  384      // x_off spatial (128*3)
#define XPAD 388      // padded x-dim of granule layout
#define OH2  382      // final output spatial

typedef __attribute__((ext_vector_type(4))) float f32x4;
typedef __attribute__((ext_vector_type(8))) __bf16 bf16x8;
typedef __attribute__((ext_vector_type(8))) unsigned short us8;
typedef __attribute__((ext_vector_type(4), aligned(4))) float f32x4u;
typedef __attribute__((ext_vector_type(2), aligned(4))) float f32x2u;

__device__ __forceinline__ void gload16(const void* gsrc, void* ldst) {
    __builtin_amdgcn_global_load_lds(
        (const __attribute__((address_space(1))) void*)gsrc,
        (__attribute__((address_space(3))) void*)ldst, 16, 0, 0);
}

// ---------------------------------------------------------------------------
// Kernel A v4: offset conv with ic-split x4 + LDS partial reduce.
// Block = 64 px (contiguous in a row) x 4 ic-quarters (16 ic each).
// 1024 blocks = 4 blocks/CU resident = 4 waves/SIMD (vs 1 for the old
// thread-per-pixel version -> the measured ~95us was occupancy-bound, R8).
// Partials go through 18KB LDS (NOT HBM - the R5 mistake), bias fused.
// Deterministic fixed-order reduction.
// ---------------------------------------------------------------------------
__global__ __launch_bounds__(256) void offset_lds4(const float* __restrict__ x,
                                                   const float* __restrict__ w_p,
                                                   const float* __restrict__ b_p,
                                                   float* __restrict__ off) {
    __shared__ float part[4][64][18];

    int t   = threadIdx.x;
    int pxl = t & 63;
    int icq = t >> 6;                 // 0..3
    int seg = blockIdx.x & 1;         // x half of the row
    int row = blockIdx.x >> 1;        // 0..511 = b*128 + py
    int py  = row & 127;
    int b   = row >> 7;
    int px  = seg * 64 + pxl;
    int ic0 = icq * 16;

    float acc[18];
#pragma unroll
    for (int co = 0; co < 18; ++co) acc[co] = 0.f;

    const float* xb = x + ((size_t)b * IC + ic0) * HH * WW;

    for (int ci = 0; ci < 16; ++ci) {
        const float* xc = xb + (size_t)ci * HH * WW;
        float xv[9];
#pragma unroll
        for (int ky = 0; ky < 3; ++ky) {
            int yy = py + ky - 1;
            bool yok = (yy >= 0) && (yy < HH);
#pragma unroll
            for (int kx = 0; kx < 3; ++kx) {
                int xx = px + kx - 1;
                bool ok = yok && (xx >= 0) && (xx < WW);
                xv[ky * 3 + kx] = ok ? xc[yy * WW + xx] : 0.f;
            }
        }
#pragma unroll
        for (int co = 0; co < 18; ++co) {
            const float* wrow = w_p + ((size_t)co * IC + ic0 + ci) * 9;
            f32x4u w0 = *(const f32x4u*)wrow;
            f32x4u w1 = *(const f32x4u*)(wrow + 4);
            float  w8 = wrow[8];
            acc[co] = fmaf(w0.x, xv[0], acc[co]);
            acc[co] = fmaf(w0.y, xv[1], acc[co]);
            acc[co] = fmaf(w0.z, xv[2], acc[co]);
            acc[co] = fmaf(w0.w, xv[3], acc[co]);
            acc[co] = fmaf(w1.x, xv[4], acc[co]);
            acc[co] = fmaf(w1.y, xv[5], acc[co]);
            acc[co] = fmaf(w1.z, xv[6], acc[co]);
            acc[co] = fmaf(w1.w, xv[7], acc[co]);
            acc[co] = fmaf(w8,   xv[8], acc[co]);
        }
    }

#pragma unroll
    for (int co = 0; co < 18; ++co) part[icq][pxl][co] = acc[co];
    __syncthreads();

    // reduce: thread (pxl, q0) handles co = q0, q0+4, ...
    for (int co = icq; co < 18; co += 4) {
        float s = b_p[co] + part[0][pxl][co] + part[1][pxl][co]
                          + part[2][pxl][co] + part[3][pxl][co];
        off[((size_t)b * 18 + co) * HH * WW + (size_t)py * WW + px] = s;
    }
}

// ---------------------------------------------------------------------------
// Kernel P (unchanged): weights -> bf16 K-step tiles Bt[s][kg:4][oc:128][e:8]
// ---------------------------------------------------------------------------
__global__ __launch_bounds__(256) void prep_w(const float* __restrict__ wc,
                                              unsigned short* __restrict__ Bt) {
    int t = blockIdx.x * 256 + threadIdx.x;
    if (t >= 18 * 4 * 128 * 8) return;
    int e  = t & 7;
    int oc = (t >> 3) & 127;
    int kg = (t >> 10) & 3;
    int s  = t >> 12;
    int ic = ((s & 1) << 5) + (kg << 3) + e;
    int kpos = s >> 1;
    int ky = kpos / 3, kx = kpos % 3;
    float v = wc[(((size_t)oc * IC + ic) * 3 + ky) * 3 + kx];
    __hip_bfloat16 h = __float2bfloat16(v);
    Bt[t] = reinterpret_cast<unsigned short&>(h);
}

// ---------------------------------------------------------------------------
// Kernel B v2 (unchanged from R9): bilinear sampling, paired dwordx2 gathers.
// ---------------------------------------------------------------------------
__global__ __launch_bounds__(256) void sample_g(const float* __restrict__ x,
                                                const float* __restrict__ off,
                                                unsigned short* __restrict__ xoff,
                                                int b0, int nwg) {
    int orig = blockIdx.x;
    int chunk = nwg >> 3;
    int wg = (orig & 7) * chunk + (orig >> 3);

    int xt  = wg % 12;
    int tmp = wg / 12;
    int yy  = tmp % XOF;
    int bl  = tmp / XOF;
    int b   = b0 + bl;
    int xx0 = xt * 32;

    int t  = threadIdx.x;
    int xl = t & 31;
    int cg = t >> 5;
    int xx = xx0 + xl;

    int j = xx / 3, kw = xx % 3;
    int i = yy / 3, kh = yy % 3;
    int n = kh * 3 + kw;

    const float* offb = off + (size_t)b * 18 * HH * WW + (size_t)i * WW + j;
    float offr = offb[(size_t)n * HH * WW];
    float offc = offb[(size_t)(n + 9) * HH * WW];

    float pr = (float)(i + kh) + offr;
    float pc = (float)(j + kw) + offc;

    float r0f = floorf(pr), c0f = floorf(pc);
    int r0 = min(max((int)r0f, 0), HP - 1);
    int c0 = min(max((int)c0f, 0), HP - 1);
    int r1 = min(max((int)(r0f + 1.f), 0), HP - 1);
    int c1 = min(max((int)(c0f + 1.f), 0), HP - 1);

    float prc = fminf(fmaxf(pr, 0.f), (float)(HP - 1));
    float pcc = fminf(fmaxf(pc, 0.f), (float)(HP - 1));

    float R0 = 1.f + ((float)r0 - prc);
    float R1 = 1.f - ((float)r1 - prc);
    float C0 = 1.f + ((float)c0 - pcc);
    float C1 = 1.f - ((float)c1 - pcc);

    int rr0 = r0 - 1, cc0 = c0 - 1, rr1 = r1 - 1, cc1 = c1 - 1;
    if (!(rr0 >= 0 && rr0 < HH)) R0 = 0.f;
    if (!(rr1 >= 0 && rr1 < HH)) R1 = 0.f;
    int ra0 = min(max(rr0, 0), HH - 1);
    int ra1 = min(max(rr1, 0), HH - 1);

    const float* xg = x + ((size_t)b * IC + cg * 8) * HH * WW;
    us8 res;

    bool fastc = (cc0 >= 0) && (cc1 == cc0 + 1) && (cc1 <= WW - 1);
    if (fastc) {
        int o0 = ra0 * WW + cc0;
        int o1 = ra1 * WW + cc0;
#pragma unroll
        for (int e = 0; e < 8; ++e) {
            const float* xc = xg + (size_t)e * HH * WW;
            f32x2u f0 = *(const f32x2u*)(xc + o0);
            f32x2u f1 = *(const f32x2u*)(xc + o1);
            float v = R0 * (C0 * f0.x + C1 * f0.y) + R1 * (C0 * f1.x + C1 * f1.y);
            __hip_bfloat16 h = __float2bfloat16(v);
            res[e] = reinterpret_cast<unsigned short&>(h);
        }
    } else {
        float C0m = (cc0 >= 0 && cc0 < WW) ? C0 : 0.f;
        float C1m = (cc1 >= 0 && cc1 < WW) ? C1 : 0.f;
        int ca0 = min(max(cc0, 0), WW - 1);
        int ca1 = min(max(cc1, 0), WW - 1);
        int o00 = ra0 * WW + ca0, o01 = ra0 * WW + ca1;
        int o10 = ra1 * WW + ca0, o11 = ra1 * WW + ca1;
#pragma unroll
        for (int e = 0; e < 8; ++e) {
            const float* xc = xg + (size_t)e * HH * WW;
            float v = R0 * (C0m * xc[o00] + C1m * xc[o01]) +
                      R1 * (C0m * xc[o10] + C1m * xc[o11]);
            __hip_bfloat16 h = __float2bfloat16(v);
            res[e] = reinterpret_cast<unsigned short&>(h);
        }
    }

    size_t di = ((((size_t)bl * XOF + yy) * 8 + cg) * XPAD + xx) * 8;
    *(us8*)(xoff + di) = res;
}

// ---------------------------------------------------------------------------
// Kernel C v5: bf16 MFMA implicit-GEMM conv — B via register prefetch.
// Bt (144KB) is L2-resident: load B fragments global->VGPR one step ahead,
// no LDS/barrier on the B path at all. LDS holds only the A slab (24KB dbuf).
// Barriers: 6 per block (A-slab swaps) instead of 18. A slab for s6+1 issued
// entirely at kx==0 (~2 steps of latency lead).
// ---------------------------------------------------------------------------
__global__ __launch_bounds__(256) void conv2_mfma(const unsigned short* __restrict__ xoff,
                                                  const unsigned short* __restrict__ Bt,
                                                  float* __restrict__ out,
                                                  int b0, int nwg) {
    __shared__ __align__(16) char lds[24576];   // A dbuf: 2 x [cg:4][px:192][16B]

    // bijective XCD-chunk swizzle (m204)
    int orig = blockIdx.x;
    int q = nwg >> 3, r = nwg & 7;
    int xcd = orig & 7, loc = orig >> 3;
    int wgid = (xcd < r ? xcd * (q + 1) : r * (q + 1) + (xcd - r) * q) + loc;

    int xt  = wgid % 3;
    int tmp = wgid / 3;
    int oy  = tmp % OH2;
    int bl  = tmp / OH2;
    int x0  = xt << 7;

    int tid  = threadIdx.x;
    int wave = tid >> 6, lane = tid & 63;
    int wm = wave >> 1;            // px half
    int wn = wave & 1;             // oc half
    int lr = lane & 15, lc = lane >> 4;

    const char* xb = (const char*)xoff + (size_t)bl * ((size_t)XOF * 8 * XPAD * 16);
    const char* bt = (const char*)Bt;
    const int boff = ((lc * 128) + wn * 64 + lr) * 16;   // per-lane offset in a B tile

    f32x4 acc[4][4];
#pragma unroll
    for (int mf = 0; mf < 4; ++mf)
#pragma unroll
        for (int nf = 0; nf < 4; ++nf)
            acc[mf][nf] = (f32x4){0.f, 0.f, 0.f, 0.f};

    // stage full A slab for super-step s6 into abuf: 3 gloads per wave.
    auto stageA_full = [&](int abuf, int s6) {
        int ky  = s6 >> 1;
        int ich = s6 & 1;
#pragma unroll
        for (int qq = 0; qq < 3; ++qq) {
            int L  = wave * 3 + qq;
            int cg = L / 3, seg = L % 3;
            const char* src = xb +
                (((size_t)(oy + ky) * 8 + ich * 4 + cg) * XPAD + x0 + seg * 64 + lane) * 16;
            char* dst = lds + abuf * 12288 + (cg * 192 + seg * 64) * 16;
            gload16(src, dst);
        }
    };

    // load B fragments for K-step t directly into registers (L2-hot).
    auto loadB = [&](bf16x8* dst, int t) {
        int s6 = t / 3, kx = t % 3;
        int sB = ((s6 >> 1) * 3 + kx) * 2 + (s6 & 1);
        const char* bsrc = bt + (size_t)sB * 8192 + boff;
#pragma unroll
        for (int nf = 0; nf < 4; ++nf)
            dst[nf] = *(const bf16x8*)(bsrc + nf * 256);
    };

    bf16x8 bcur[4], bnxt[4];

    stageA_full(0, 0);
    loadB(bcur, 0);
    __syncthreads();                 // drains prologue A gloads

    int abuf = 0;
    for (int s6 = 0; s6 < 6; ++s6) {
#pragma unroll
        for (int kx = 0; kx < 3; ++kx) {
            int t = s6 * 3 + kx;
            if (t + 1 < 18) loadB(bnxt, t + 1);
            if (kx == 0 && s6 + 1 < 6) stageA_full(abuf ^ 1, s6 + 1);

            const char* abase = lds + abuf * 12288;
            bf16x8 af[4];
#pragma unroll
            for (int mf = 0; mf < 4; ++mf)
                af[mf] = *(const bf16x8*)(abase +
                    (lc * 192 + wm * 64 + mf * 16 + lr + kx) * 16);
#pragma unroll
            for (int mf = 0; mf < 4; ++mf)
#pragma unroll
                for (int nf = 0; nf < 4; ++nf)
                    acc[mf][nf] = __builtin_amdgcn_mfma_f32_16x16x32_bf16(
                        af[mf], bcur[nf], acc[mf][nf], 0, 0, 0);
#pragma unroll
            for (int nf = 0; nf < 4; ++nf) bcur[nf] = bnxt[nf];
        }
        if (s6 + 1 < 6) {
            __syncthreads();         // A slab swap (6 barriers total)
            abuf ^= 1;
        }
    }

    int b = b0 + bl;
#pragma unroll
    for (int mf = 0; mf < 4; ++mf) {
        int ox0 = x0 + wm * 64 + mf * 16 + (lc << 2);
#pragma unroll
        for (int nf = 0; nf < 4; ++nf) {
            int oc = wn * 64 + nf * 16 + lr;
            float* po = out + (((size_t)b * OC + oc) * OH2 + oy) * OH2 + ox0;
            if (ox0 + 3 < OH2) {
                *(f32x4u*)po = acc[mf][nf];
            } else {
#pragma unroll
                for (int rr = 0; rr < 4; ++rr)
                    if (ox0 + rr < OH2) po[rr] = acc[mf][nf][rr];
            }
        }
    }
}

// ---------------------------------------------------------------------------
extern "C" void kernel_launch(void* const* d_in, const int* in_sizes, int n_in,
                              void* d_out, int out_size, void* d_ws, size_t ws_size,
                              hipStream_t stream) {
    const float* x      = (const float*)d_in[0];
    const float* w_p    = (const float*)d_in[1];
    const float* b_p    = (const float*)d_in[2];
    const float* w_conv = (const float*)d_in[3];
    float* out = (float*)d_out;

    const size_t offElems = (size_t)B_ * 18 * HH * WW;          // f32
    const size_t btElems  = (size_t)18 * 4 * 128 * 8;           // bf16
    const size_t xofElems = (size_t)XOF * 8 * XPAD * 8;         // bf16 per batch
    const size_t slack    = 16384;

    float* off = (float*)d_ws;
    unsigned short* Bt   = (unsigned short*)(off + offElems);
    unsigned short* xoff = Bt + btElems;

    const size_t headBytes = offElems * 4 + btElems * 2;
    const bool allBatch = ws_size >= headBytes + 4 * xofElems * 2 + slack;

    prep_w<<<(int)((btElems + 255) / 256), 256, 0, stream>>>(w_conv, Bt);
    offset_lds4<<<1024, 256, 0, stream>>>(x, w_p, b_p, off);

    if (allBatch) {
        int snwg = 12 * XOF * B_;                 // 18432
        sample_g<<<snwg, 256, 0, stream>>>(x, off, xoff, 0, snwg);
        int cnwg = 3 * OH2 * B_;                  // 4584
        conv2_mfma<<<cnwg, 256, 0, stream>>>(xoff, Bt, out, 0, cnwg);
    } else {
        for (int b = 0; b < B_; ++b) {
            int snwg = 12 * XOF;                  // 4608
            sample_g<<<snwg, 256, 0, stream>>>(x, off, xoff, b, snwg);
            int cnwg = 3 * OH2;                   // 1146
            conv2_mfma<<<cnwg, 256, 0, stream>>>(xoff, Bt, out, b, cnwg);
        }
    }
}

// Round 11
// 249.116 us; speedup vs baseline: 6.0124x; 1.2575x over previous
//
#include <hip/hip_runtime.h>
#include <hip/hip_bf16.h>

#define B_   4
#define IC   64
#define OC   128
#define HH   128
#define WW   128
#define HP   130      // padded H/W for sampling
#define XOF  384      // x_off spatial (128*3)
#define XPAD 388      // padded x-dim of granule layout
#define OH2  382      // final output spatial

typedef __attribute__((ext_vector_type(4))) float f32x4;
typedef __attribute__((ext_vector_type(8))) __bf16 bf16x8;
typedef __attribute__((ext_vector_type(8))) unsigned short us8;
typedef __attribute__((ext_vector_type(4), aligned(4))) float f32x4u;

__device__ __forceinline__ void gload16(const void* gsrc, void* ldst) {
    __builtin_amdgcn_global_load_lds(
        (const __attribute__((address_space(1))) void*)gsrc,
        (__attribute__((address_space(3))) void*)ldst, 16, 0, 0);
}

// ---------------------------------------------------------------------------
// Kernel T: NCHW -> NHWC fp32 transpose of x (16.8 MB), LDS-tiled.
// Block = one (b, y, 32-px tile): read coalesced along x, write coalesced
// along c. tile padded [64][33] -> conflict-free both phases.
// ---------------------------------------------------------------------------
__global__ __launch_bounds__(256) void nchw2nhwc(const float* __restrict__ x,
                                                 float* __restrict__ xt) {
    __shared__ float tile[64][33];
    int bid = blockIdx.x;              // 4*128*4 = 2048
    int xt4 = bid & 3;
    int y   = (bid >> 2) & 127;
    int b   = bid >> 9;
    int x0  = xt4 * 32;

    int t  = threadIdx.x;
    int xl = t & 31;
    int c8 = t >> 5;
#pragma unroll
    for (int it = 0; it < 8; ++it) {
        int c = it * 8 + c8;
        tile[c][xl] = x[(((size_t)b * IC + c) * HH + y) * WW + x0 + xl];
    }
    __syncthreads();
    int c  = t & 63;
    int xw = t >> 6;
#pragma unroll
    for (int it = 0; it < 8; ++it) {
        int xx = it * 4 + xw;
        xt[(((size_t)b * HH + y) * WW + x0 + xx) * IC + c] = tile[c][xx];
    }
}

// ---------------------------------------------------------------------------
// Kernel A v5: offset conv, ic-split x4 + LDS partial reduce, with
// readfirstlane-scalarized weight base: w_p addresses become provably
// wave-uniform -> s_load on the SMEM pipe instead of ~900 per-lane VMEM
// loads per thread (the suspected true cost of every offset variant so far).
// ---------------------------------------------------------------------------
__global__ __launch_bounds__(256) void offset_lds4(const float* __restrict__ x,
                                                   const float* __restrict__ w_p,
                                                   const float* __restrict__ b_p,
                                                   float* __restrict__ off) {
    __shared__ float part[4][64][18];

    int t   = threadIdx.x;
    int pxl = t & 63;
    int icq = t >> 6;                 // 0..3 == wave index
    int seg = blockIdx.x & 1;
    int row = blockIdx.x >> 1;
    int py  = row & 127;
    int b   = row >> 7;
    int px  = seg * 64 + pxl;
    int ic0 = __builtin_amdgcn_readfirstlane(icq << 4);   // wave-uniform SGPR

    float acc[18];
#pragma unroll
    for (int co = 0; co < 18; ++co) acc[co] = 0.f;

    const float* xb = x + ((size_t)b * IC + ic0) * HH * WW;

    for (int ci = 0; ci < 16; ++ci) {
        const float* xc = xb + (size_t)ci * HH * WW;
        float xv[9];
#pragma unroll
        for (int ky = 0; ky < 3; ++ky) {
            int yy = py + ky - 1;
            bool yok = (yy >= 0) && (yy < HH);
#pragma unroll
            for (int kx = 0; kx < 3; ++kx) {
                int xx = px + kx - 1;
                bool ok = yok && (xx >= 0) && (xx < WW);
                xv[ky * 3 + kx] = ok ? xc[yy * WW + xx] : 0.f;
            }
        }
#pragma unroll
        for (int co = 0; co < 18; ++co) {
            const float* wrow = w_p + ((size_t)co * IC + ic0 + ci) * 9;
            f32x4u w0 = *(const f32x4u*)wrow;
            f32x4u w1 = *(const f32x4u*)(wrow + 4);
            float  w8 = wrow[8];
            acc[co] = fmaf(w0.x, xv[0], acc[co]);
            acc[co] = fmaf(w0.y, xv[1], acc[co]);
            acc[co] = fmaf(w0.z, xv[2], acc[co]);
            acc[co] = fmaf(w0.w, xv[3], acc[co]);
            acc[co] = fmaf(w1.x, xv[4], acc[co]);
            acc[co] = fmaf(w1.y, xv[5], acc[co]);
            acc[co] = fmaf(w1.z, xv[6], acc[co]);
            acc[co] = fmaf(w1.w, xv[7], acc[co]);
            acc[co] = fmaf(w8,   xv[8], acc[co]);
        }
    }

#pragma unroll
    for (int co = 0; co < 18; ++co) part[icq][pxl][co] = acc[co];
    __syncthreads();

    for (int co = icq; co < 18; co += 4) {
        float s = b_p[co] + part[0][pxl][co] + part[1][pxl][co]
                          + part[2][pxl][co] + part[3][pxl][co];
        off[((size_t)b * 18 + co) * HH * WW + (size_t)py * WW + px] = s;
    }
}

// ---------------------------------------------------------------------------
// Kernel P (unchanged): weights -> bf16 K-step tiles Bt[s][kg:4][oc:128][e:8]
// ---------------------------------------------------------------------------
__global__ __launch_bounds__(256) void prep_w(const float* __restrict__ wc,
                                              unsigned short* __restrict__ Bt) {
    int t = blockIdx.x * 256 + threadIdx.x;
    if (t >= 18 * 4 * 128 * 8) return;
    int e  = t & 7;
    int oc = (t >> 3) & 127;
    int kg = (t >> 10) & 3;
    int s  = t >> 12;
    int ic = ((s & 1) << 5) + (kg << 3) + e;
    int kpos = s >> 1;
    int ky = kpos / 3, kx = kpos % 3;
    float v = wc[(((size_t)oc * IC + ic) * 3 + ky) * 3 + kx];
    __hip_bfloat16 h = __float2bfloat16(v);
    Bt[t] = reinterpret_cast<unsigned short&>(h);
}

// ---------------------------------------------------------------------------
// Kernel B v3: bilinear sampling from NHWC x. Branchless unified path
// (== v2's slow path bitwise). Each corner = 8 contiguous channels = two
// dwordx4 loads: 8 x dwordx4 per thread, 2 fully-used cache lines per
// pixel-corner (vs 8 lines at 8B each in NCHW).
// ---------------------------------------------------------------------------
__global__ __launch_bounds__(256) void sample_nhwc(const float* __restrict__ xt,
                                                   const float* __restrict__ off,
                                                   unsigned short* __restrict__ xoff,
                                                   int b0, int nwg) {
    int orig = blockIdx.x;
    int chunk = nwg >> 3;
    int wg = (orig & 7) * chunk + (orig >> 3);

    int xtile = wg % 12;
    int tmp = wg / 12;
    int yy  = tmp % XOF;
    int bl  = tmp / XOF;
    int b   = b0 + bl;
    int xx0 = xtile * 32;

    int t  = threadIdx.x;
    int xl = t & 31;
    int cg = t >> 5;
    int xx = xx0 + xl;

    int j = xx / 3, kw = xx % 3;
    int i = yy / 3, kh = yy % 3;
    int n = kh * 3 + kw;

    const float* offb = off + (size_t)b * 18 * HH * WW + (size_t)i * WW + j;
    float offr = offb[(size_t)n * HH * WW];
    float offc = offb[(size_t)(n + 9) * HH * WW];

    float pr = (float)(i + kh) + offr;
    float pc = (float)(j + kw) + offc;

    float r0f = floorf(pr), c0f = floorf(pc);
    int r0 = min(max((int)r0f, 0), HP - 1);
    int c0 = min(max((int)c0f, 0), HP - 1);
    int r1 = min(max((int)(r0f + 1.f), 0), HP - 1);
    int c1 = min(max((int)(c0f + 1.f), 0), HP - 1);

    float prc = fminf(fmaxf(pr, 0.f), (float)(HP - 1));
    float pcc = fminf(fmaxf(pc, 0.f), (float)(HP - 1));

    float R0 = 1.f + ((float)r0 - prc);
    float R1 = 1.f - ((float)r1 - prc);
    float C0 = 1.f + ((float)c0 - pcc);
    float C1 = 1.f - ((float)c1 - pcc);

    int rr0 = r0 - 1, cc0 = c0 - 1, rr1 = r1 - 1, cc1 = c1 - 1;
    if (!(rr0 >= 0 && rr0 < HH)) R0 = 0.f;
    if (!(rr1 >= 0 && rr1 < HH)) R1 = 0.f;
    float C0m = (cc0 >= 0 && cc0 < WW) ? C0 : 0.f;
    float C1m = (cc1 >= 0 && cc1 < WW) ? C1 : 0.f;
    int ra0 = min(max(rr0, 0), HH - 1);
    int ra1 = min(max(rr1, 0), HH - 1);
    int ca0 = min(max(cc0, 0), WW - 1);
    int ca1 = min(max(cc1, 0), WW - 1);

    const float* xb = xt + (size_t)b * HH * WW * IC + cg * 8;
    const float* p00 = xb + ((size_t)ra0 * WW + ca0) * IC;
    const float* p01 = xb + ((size_t)ra0 * WW + ca1) * IC;
    const float* p10 = xb + ((size_t)ra1 * WW + ca0) * IC;
    const float* p11 = xb + ((size_t)ra1 * WW + ca1) * IC;

    us8 res;
#pragma unroll
    for (int h = 0; h < 2; ++h) {
        f32x4u a  = *(const f32x4u*)(p00 + h * 4);
        f32x4u bb = *(const f32x4u*)(p01 + h * 4);
        f32x4u cc = *(const f32x4u*)(p10 + h * 4);
        f32x4u dd = *(const f32x4u*)(p11 + h * 4);
#pragma unroll
        for (int e = 0; e < 4; ++e) {
            float v = R0 * (C0m * a[e] + C1m * bb[e]) +
                      R1 * (C0m * cc[e] + C1m * dd[e]);
            __hip_bfloat16 hh = __float2bfloat16(v);
            res[h * 4 + e] = reinterpret_cast<unsigned short&>(hh);
        }
    }

    size_t di = ((((size_t)bl * XOF + yy) * 8 + cg) * XPAD + xx) * 8;
    *(us8*)(xoff + di) = res;
}

// ---------------------------------------------------------------------------
// Kernel C v5 (byte-identical to R10): bf16 MFMA implicit-GEMM conv,
// B via register prefetch, 6 barriers/block.
// ---------------------------------------------------------------------------
__global__ __launch_bounds__(256) void conv2_mfma(const unsigned short* __restrict__ xoff,
                                                  const unsigned short* __restrict__ Bt,
                                                  float* __restrict__ out,
                                                  int b0, int nwg) {
    __shared__ __align__(16) char lds[24576];   // A dbuf: 2 x [cg:4][px:192][16B]

    // bijective XCD-chunk swizzle (m204)
    int orig = blockIdx.x;
    int q = nwg >> 3, r = nwg & 7;
    int xcd = orig & 7, loc = orig >> 3;
    int wgid = (xcd < r ? xcd * (q + 1) : r * (q + 1) + (xcd - r) * q) + loc;

    int xt  = wgid % 3;
    int tmp = wgid / 3;
    int oy  = tmp % OH2;
    int bl  = tmp / OH2;
    int x0  = xt << 7;

    int tid  = threadIdx.x;
    int wave = tid >> 6, lane = tid & 63;
    int wm = wave >> 1;            // px half
    int wn = wave & 1;             // oc half
    int lr = lane & 15, lc = lane >> 4;

    const char* xb = (const char*)xoff + (size_t)bl * ((size_t)XOF * 8 * XPAD * 16);
    const char* bt = (const char*)Bt;
    const int boff = ((lc * 128) + wn * 64 + lr) * 16;

    f32x4 acc[4][4];
#pragma unroll
    for (int mf = 0; mf < 4; ++mf)
#pragma unroll
        for (int nf = 0; nf < 4; ++nf)
            acc[mf][nf] = (f32x4){0.f, 0.f, 0.f, 0.f};

    auto stageA_full = [&](int abuf, int s6) {
        int ky  = s6 >> 1;
        int ich = s6 & 1;
#pragma unroll
        for (int qq = 0; qq < 3; ++qq) {
            int L  = wave * 3 + qq;
            int cg = L / 3, seg = L % 3;
            const char* src = xb +
                (((size_t)(oy + ky) * 8 + ich * 4 + cg) * XPAD + x0 + seg * 64 + lane) * 16;
            char* dst = lds + abuf * 12288 + (cg * 192 + seg * 64) * 16;
            gload16(src, dst);
        }
    };

    auto loadB = [&](bf16x8* dst, int t) {
        int s6 = t / 3, kx = t % 3;
        int sB = ((s6 >> 1) * 3 + kx) * 2 + (s6 & 1);
        const char* bsrc = bt + (size_t)sB * 8192 + boff;
#pragma unroll
        for (int nf = 0; nf < 4; ++nf)
            dst[nf] = *(const bf16x8*)(bsrc + nf * 256);
    };

    bf16x8 bcur[4], bnxt[4];

    stageA_full(0, 0);
    loadB(bcur, 0);
    __syncthreads();

    int abuf = 0;
    for (int s6 = 0; s6 < 6; ++s6) {
#pragma unroll
        for (int kx = 0; kx < 3; ++kx) {
            int t = s6 * 3 + kx;
            if (t + 1 < 18) loadB(bnxt, t + 1);
            if (kx == 0 && s6 + 1 < 6) stageA_full(abuf ^ 1, s6 + 1);

            const char* abase = lds + abuf * 12288;
            bf16x8 af[4];
#pragma unroll
            for (int mf = 0; mf < 4; ++mf)
                af[mf] = *(const bf16x8*)(abase +
                    (lc * 192 + wm * 64 + mf * 16 + lr + kx) * 16);
#pragma unroll
            for (int mf = 0; mf < 4; ++mf)
#pragma unroll
                for (int nf = 0; nf < 4; ++nf)
                    acc[mf][nf] = __builtin_amdgcn_mfma_f32_16x16x32_bf16(
                        af[mf], bcur[nf], acc[mf][nf], 0, 0, 0);
#pragma unroll
            for (int nf = 0; nf < 4; ++nf) bcur[nf] = bnxt[nf];
        }
        if (s6 + 1 < 6) {
            __syncthreads();
            abuf ^= 1;
        }
    }

    int b = b0 + bl;
#pragma unroll
    for (int mf = 0; mf < 4; ++mf) {
        int ox0 = x0 + wm * 64 + mf * 16 + (lc << 2);
#pragma unroll
        for (int nf = 0; nf < 4; ++nf) {
            int oc = wn * 64 + nf * 16 + lr;
            float* po = out + (((size_t)b * OC + oc) * OH2 + oy) * OH2 + ox0;
            if (ox0 + 3 < OH2) {
                *(f32x4u*)po = acc[mf][nf];
            } else {
#pragma unroll
                for (int rr = 0; rr < 4; ++rr)
                    if (ox0 + rr < OH2) po[rr] = acc[mf][nf][rr];
            }
        }
    }
}

// ---------------------------------------------------------------------------
extern "C" void kernel_launch(void* const* d_in, const int* in_sizes, int n_in,
                              void* d_out, int out_size, void* d_ws, size_t ws_size,
                              hipStream_t stream) {
    const float* x      = (const float*)d_in[0];
    const float* w_p    = (const float*)d_in[1];
    const float* b_p    = (const float*)d_in[2];
    const float* w_conv = (const float*)d_in[3];
    float* out = (float*)d_out;

    const size_t offElems = (size_t)B_ * 18 * HH * WW;          // f32
    const size_t xtElems  = (size_t)B_ * HH * WW * IC;          // f32 NHWC copy
    const size_t btElems  = (size_t)18 * 4 * 128 * 8;           // bf16
    const size_t xofElems = (size_t)XOF * 8 * XPAD * 8;         // bf16 per batch
    const size_t slack    = 16384;

    float* off = (float*)d_ws;
    float* xtb = off + offElems;
    unsigned short* Bt   = (unsigned short*)(xtb + xtElems);
    unsigned short* xoff = Bt + btElems;

    const size_t headBytes = (offElems + xtElems) * 4 + btElems * 2;
    const bool allBatch = ws_size >= headBytes + 4 * xofElems * 2 + slack;

    prep_w<<<(int)((btElems + 255) / 256), 256, 0, stream>>>(w_conv, Bt);
    nchw2nhwc<<<2048, 256, 0, stream>>>(x, xtb);
    offset_lds4<<<1024, 256, 0, stream>>>(x, w_p, b_p, off);

    if (allBatch) {
        int snwg = 12 * XOF * B_;                 // 18432
        sample_nhwc<<<snwg, 256, 0, stream>>>(xtb, off, xoff, 0, snwg);
        int cnwg = 3 * OH2 * B_;                  // 4584
        conv2_mfma<<<cnwg, 256, 0, stream>>>(xoff, Bt, out, 0, cnwg);
    } else {
        for (int b = 0; b < B_; ++b) {
            int snwg = 12 * XOF;                  // 4608
            sample_nhwc<<<snwg, 256, 0, stream>>>(xtb, off, xoff, b, snwg);
            int cnwg = 3 * OH2;                   // 1146
            conv2_mfma<<<cnwg, 256, 0, stream>>>(xoff, Bt, out, b, cnwg);
        }
    }
}